// Round 14
// baseline (83.411 us; speedup 1.0000x reference)
//
#include <hip/hip_runtime.h>

#define NEARV    0.2f
#define LOWPASSV 0.3f

constexpr int HH = 80, WW = 80;
constexpr int CFE = 32;          // feature channels
constexpr int NZ = 6;            // z-levels per (x,y) cell (grid 32x32x6)

constexpr int NCELL = 1024;      // N / NZ
constexpr int HMAX = NCELL * NZ; // 6144 header slots per camera

typedef unsigned long long u64;
typedef unsigned int u32;

// ------- Kernel R: rank-by-counting cell argsort (R11/R13 verbatim, ~8.5us) -------
// Keys (HW-verified R7/R8/R10/R11/R13, absmax bit-identical): depth in
// (0.2,32) -> floatbits - 0x3E000000 monotone 26-bit; >>4 to 22 bits;
// packed = (key22<<10)|cell UNIQUE -> rank(e) = #{keys < key(e)} == stable
// depth argsort position; ranks are a permutation -> cellord[rank] = cell.
__global__ __launch_bounds__(512) void rank_kernel(
    const float* __restrict__ pc_xyz, const float* __restrict__ cam_rot,
    const float* __restrict__ cam_trans, int N,
    int* __restrict__ counts, int* __restrict__ cellord)
{
  __shared__ u32 sk[NCELL];              // 4 KB
  __shared__ u32 wred[8];

  const int cam = blockIdx.y;
  const int tid = threadIdx.x;           // 0..511
  const float* R = cam_rot + cam*9;
  const float R20 = R[6], R21 = R[7], R22 = R[8];
  const float t2  = cam_trans[cam*3+2];

  int vcnt = 0;
  #pragma unroll
  for (int e2 = 0; e2 < NCELL/512; ++e2) {
    const int cell = e2*512 + tid;
    const int i0 = cell * NZ;
    u32 key22 = 0x3FFFFFu;               // invalid marker: sorts last
    if (i0 < N) {
      float c2 = R20*pc_xyz[i0*3+0] + R21*pc_xyz[i0*3+1] + R22*pc_xyz[i0*3+2] + t2;
      if (c2 > NEARV) {
        u32 b = __float_as_uint(c2) - 0x3E000000u;   // monotone, 26 bits
        b = b < 0x03FFFF00u ? b : 0x03FFFF00u;       // clamp below marker
        key22 = b >> 4;                              // 22 bits, < 0x3FFFFF
        ++vcnt;
      }
    }
    sk[cell] = (key22 << 10) | (u32)cell;
  }
  __syncthreads();

  // rank: threads (2c, 2c+1) handle cell c; each counts half the keys
  const int cell = blockIdx.x * 256 + (tid >> 1);
  const u32 mykey = sk[cell];
  const uint4* k4 = (const uint4*)sk;
  const int h0 = (tid & 1) * (NCELL/8);  // half offset in uint4 units
  int rank = 0;
  #pragma unroll 8
  for (int i = 0; i < NCELL/8; ++i) {
    const uint4 kv = k4[h0 + i];
    rank += (int)(kv.x < mykey) + (int)(kv.y < mykey)
          + (int)(kv.z < mykey) + (int)(kv.w < mykey);
  }
  rank += __shfl_xor(rank, 1, 64);       // combine halves (same wave)

  if ((tid & 1) == 0)
    cellord[(size_t)cam * NCELL + rank] = cell;

  if (blockIdx.x == 0) {
    #pragma unroll
    for (int off = 32; off > 0; off >>= 1) vcnt += __shfl_down(vcnt, off, 64);
    if ((tid & 63) == 0) wred[tid >> 6] = (u32)vcnt;
    __syncthreads();
    if (tid == 0) {
      u32 tot = 0;
      #pragma unroll
      for (int w = 0; w < 8; ++w) tot += wred[w];
      counts[cam] = (int)tot * NZ;
    }
  }
}

// ------------- Kernel P: wide projection with BAKED alpha constants (R14) -------------
// One thread per (camera, sorted gaussian), 144 blocks spread across CUs.
// R14: bake -0.5*log2(e) into the quadratic-form constants so the render's
// alpha is 3 muls + 3 fmas + native exp2 (v_exp_f32 IS 2^x; kills the ln2
// mul inside __expf). power_l2 = log2(e)*power -> identical math, <=1ulp.
// Headers: hdrA=(u, v, A2, B2), hdrB=(C2, op, r2, gi_bits) where
// A2=-0.5*ia*L, C2=-0.5*ic*L, B2=+bb*idet*L, L=log2(e).
// Off-screen gaussians get r2 = -1 (render cull rejects; bit-exact removal).
// KEY ALGEBRA (verified): scales is SCALAR per gaussian, Mcov = s*Rg,
// Rg rotation => cov = s^2 * J*J^T.
__global__ __launch_bounds__(256) void proj_kernel(
    const float* __restrict__ pc_xyz, const float* __restrict__ cam_rot,
    const float* __restrict__ cam_trans, const float* __restrict__ cam_intr,
    const float* __restrict__ density, const float* __restrict__ scales,
    int N, int NC,
    const int* __restrict__ counts, const int* __restrict__ cellord,
    float4* __restrict__ hdrA, float4* __restrict__ hdrB)
{
  const int cam = blockIdx.y;
  const int kq = blockIdx.x * 256 + threadIdx.x;
  if (kq >= counts[cam]) return;

  const int cellp = kq / NZ;
  const int n = cellord[(size_t)cam * NCELL + cellp] * NZ + (kq - cellp * NZ);

  const float* R = cam_rot + cam*9;
  const float* t = cam_trans + cam*3;
  const float* intr = cam_intr + cam*4;
  const float fx = intr[0], fy = intr[1], cx = intr[2], cy = intr[3];
  const int b = cam / NC;

  const float p0 = pc_xyz[n*3+0], p1 = pc_xyz[n*3+1], p2 = pc_xyz[n*3+2];
  const float c0 = R[0]*p0 + R[1]*p1 + R[2]*p2 + t[0];
  const float c1 = R[3]*p0 + R[4]*p1 + R[5]*p2 + t[1];
  const float c2 = R[6]*p0 + R[7]*p1 + R[8]*p2 + t[2];
  const float tz = fmaxf(c2, 1e-6f);
  const float itz = 1.0f / tz;
  const float u = fx*c0*itz + cx;
  const float v = fy*c1*itz + cy;
  const float j00 = fx*itz, j02 = -(fx*c0*itz)*itz;
  const float j11 = fy*itz, j12 = -(fy*c1*itz)*itz;
  const float s = expf(scales[n]);
  const float s2 = s*s;
  const float cov00 = s2*(j00*j00 + j02*j02);
  const float cov01 = s2*(j02*j12);
  const float cov11 = s2*(j11*j11 + j12*j12);
  const float a = cov00 + LOWPASSV, bb = cov01, cc = cov11 + LOWPASSV;
  const float det = a*cc - bb*bb;
  const float idet = 1.0f / det;
  // conservative cull radius: dist^2 > r2 <=> power < -16 everywhere
  const float mid = 0.5f*(a + cc);
  const float dd = sqrtf(fmaxf(mid*mid - det, 0.f));
  float r2 = 32.f * (mid + dd);
  const float dens = density[(size_t)b*N + n];
  const float op = fmaxf(dens, 0.f) + log1pf(expf(-fabsf(dens)));  // softplus
  // whole-SCREEN rect cull -> r2 = -1 disables this gaussian in the render
  const float sx = fminf(fmaxf(u, 0.f), (float)(WW-1)) - u;
  const float sy = fminf(fmaxf(v, 0.f), (float)(HH-1)) - v;
  if (sx*sx + sy*sy > r2) r2 = -1.0f;

  const float L = 1.4426950408889634f;   // log2(e)
  const float A2 = -0.5f * (cc*idet) * L;
  const float C2 = -0.5f * (a*idet)  * L;
  const float B2 =         (bb*idet) * L;

  hdrA[(size_t)cam * HMAX + kq] = make_float4(u, v, A2, B2);
  hdrB[(size_t)cam * HMAX + kq] = make_float4(C2, op, r2, __int_as_float(n));
}

// ---------- Kernel B: barrier-free compositing, alpha-first scheduling (R14) ----------
// R13 post-mortem: render ~29us in EVERY variant (ledger closed via R7/R3
// direct measurements) => bound by (1) the alpha VALU chain on wall-gating
// tiles (channel-split halving accumulate was neutral => alpha dominates)
// and (2) the post-cull serial group-0 feature gather (~400cy, index known
// only after this chunk's ballot -- never hidden by header prefetch).
// R14: (1) baked-constant alpha: pl2 = A2*dx^2 + C2*dy^2 + B2*dxdy, native
// exp2, threshold -23.083 (= -16*log2e) -> ~25% fewer alpha ops.
// (2) alpha-first group loop: al[8] uses only cA/cB, so it runs WHILE the
// group-0 gather is in flight; sfeat publish (the vmcnt wait) moves after.
// Single-wave block, no __syncthreads (R13, passed bit-identical).
__global__ __launch_bounds__(64) void render_kernel(
    const float* __restrict__ vox,
    const float4* __restrict__ hdrA, const float4* __restrict__ hdrB,
    const int* __restrict__ counts,
    float* __restrict__ out, int N, int NC)
{
  __shared__ float4 cA[64], cB[64];     // compacted survivor headers (2 KB)
  __shared__ int   cgi[64];             // compacted survivor original index
  __shared__ float4 sfeat[64];          // current 8 survivors' features (1 KB)

  const int cam = blockIdx.y;
  const int tile = blockIdx.x;          // 10 x 20 tiles of 8x4 px
  const int tx = tile % (WW/8), ty = tile / (WW/8);
  const int lane = threadIdx.x;
  const int p  = lane & 31;             // pixel id within tile (32 px)
  const int h  = lane >> 5;             // channel half: [16h, 16h+16)
  const int lx = p & 7, ly = p >> 3;
  const int px = tx*8 + lx, py = ty*4 + ly;
  const float fpx = (float)px, fpy = (float)py;
  const float tx0 = (float)(tx*8), tx1 = tx0 + 7.f;
  const float ty0 = (float)(ty*4), ty1 = ty0 + 3.f;
  const int count = counts[cam];
  const int b = cam / NC;
  const float4* hA = hdrA + (size_t)cam * HMAX;
  const float4* hB = hdrB + (size_t)cam * HMAX;
  const float4* voxb = (const float4*)vox + (size_t)b * N * (CFE/4);

  float acc[CFE/2];                     // this lane's 16 channels
  #pragma unroll
  for (int i = 0; i < CFE/2; ++i) acc[i] = 0.f;
  float T = 1.0f;
  bool done = false;

#define LOAD4(Aarr, Barr, base_) do {                                   \
    _Pragma("unroll")                                                   \
    for (int d_ = 0; d_ < 4; ++d_) {                                    \
      const int kn_ = min((base_) + d_*64 + lane, count - 1);           \
      Aarr[d_] = hA[kn_]; Barr[d_] = hB[kn_];                           \
    } } while (0)

// one 64-gaussian chunk: cull -> compact -> alpha-first composite.
// NO __syncthreads: single-wave block, in-order DS unit + compiler lgkmcnt
// dependency waits give cross-lane LDS ordering (R13, HW-verified).
#define PROCESS_CHUNK(k0_, a0_, b0_) do {                               \
    const int ki = (k0_) + lane;                                        \
    const float ddx = fminf(fmaxf((a0_).x, tx0), tx1) - (a0_).x;        \
    const float ddy = fminf(fmaxf((a0_).y, ty0), ty1) - (a0_).y;        \
    const bool hit = (ki < count) && (ddx*ddx + ddy*ddy <= (b0_).z);    \
    const u64 m = __ballot(hit);                                        \
    const int P = __popcll(m);                                          \
    if (P == 0) continue;                                               \
    if (hit) {                                                          \
      const int pos = (int)__popcll(m & ((1ull << lane) - 1ull));       \
      cA[pos] = (a0_); cB[pos] = (b0_);                                 \
      cgi[pos] = __float_as_int((b0_).w);                               \
    }                                                                   \
    __builtin_amdgcn_wave_barrier();  /* keep DS order: compact < reads */ \
    const int sl = lane >> 3, sc = lane & 7;                            \
    float4 pf = voxb[(size_t)cgi[min(sl, P - 1)] * (CFE/4) + sc];       \
    for (int j = 0; j < P; j += 8) {                                    \
      /* alpha FIRST: needs only cA/cB -- overlaps the pf gather */     \
      float al[8];                                                      \
      _Pragma("unroll")                                                 \
      for (int qq = 0; qq < 8; ++qq) {                                  \
        const int idx = j + qq;                                         \
        const float4 a1 = cA[idx & 63];   /* (u, v, A2, B2) */          \
        const float4 a2 = cB[idx & 63];   /* (C2, op, r2, gi) */        \
        const float dx = fpx - a1.x, dy = fpy - a1.y;                   \
        const float q1 = dx*dx, q2 = dy*dy, q3 = dx*dy;                 \
        const float pl2 = a1.z*q1 + a2.x*q2 + a1.w*q3;  /* log2 power */ \
        float av = fminf(a2.y * __builtin_exp2f(fminf(pl2, 0.f)), 0.99f); \
        av = (pl2 > -23.0831f) ? av : 0.f;  /* 2^-23.08 = 1.1e-7 */     \
        al[qq] = (idx < P) ? av : 0.f;                                  \
      }                                                                 \
      sfeat[lane] = pf;                 /* vmcnt wait: gather now done */ \
      if (j + 8 < P) {                  /* gather next group */          \
        const int si = min(j + 8 + sl, P - 1);                          \
        pf = voxb[(size_t)cgi[si] * (CFE/4) + sc];                      \
      }                                                                 \
      __builtin_amdgcn_wave_barrier(); /* publish < composite reads */  \
      _Pragma("unroll")                                                 \
      for (int qq = 0; qq < 8; ++qq) {                                  \
        const float w = T * al[qq];                                     \
        T -= w;                                                         \
        if (__any(w > 1e-8f)) {                                         \
          const float4* fj = &sfeat[qq * 8 + 4 * h];                    \
          _Pragma("unroll")                                             \
          for (int c4 = 0; c4 < 4; ++c4) {                              \
            const float4 fv = fj[c4];                                   \
            acc[c4*4+0] = fmaf(w, fv.x, acc[c4*4+0]);                   \
            acc[c4*4+1] = fmaf(w, fv.y, acc[c4*4+1]);                   \
            acc[c4*4+2] = fmaf(w, fv.z, acc[c4*4+2]);                   \
            acc[c4*4+3] = fmaf(w, fv.w, acc[c4*4+3]);                   \
          }                                                             \
        }                                                               \
      }                                                                 \
      if (__all(T < 1e-3f)) { done = true; break; }                     \
      __builtin_amdgcn_wave_barrier(); /* reads < next publish (WAR) */ \
    }                                                                   \
  } while (0)

  if (count > 0) {
    float4 A0x[4], B0x[4], A1x[4], B1x[4];
    const int nquad = (count + 255) >> 8;   // groups of 4 chunks
    LOAD4(A0x, B0x, 0);

    for (int q = 0; q < nquad && !done; q += 2) {
      // even quad: consume A0x/B0x, prefetch next quad into A1x/B1x
      if (q + 1 < nquad) LOAD4(A1x, B1x, (q+1)*256);
      #pragma unroll
      for (int d = 0; d < 4; ++d) {
        if (done) break;
        const int k0 = q*256 + d*64;
        if (k0 >= count) break;
        PROCESS_CHUNK(k0, A0x[d], B0x[d]);
      }
      if (done || q + 1 >= nquad) break;
      // odd quad: consume A1x/B1x, prefetch next quad into A0x/B0x
      if (q + 2 < nquad) LOAD4(A0x, B0x, (q+2)*256);
      #pragma unroll
      for (int d = 0; d < 4; ++d) {
        if (done) break;
        const int k0 = (q+1)*256 + d*64;
        if (k0 >= count) break;
        PROCESS_CHUNK(k0, A1x[d], B1x[d]);
      }
    }
  }
#undef PROCESS_CHUNK
#undef LOAD4

  // write this lane's 16 channels for its pixel
  float* ob = out + (((size_t)cam * CFE + 16*h) * HH + py) * WW + px;
  #pragma unroll
  for (int c = 0; c < CFE/2; ++c) ob[(size_t)c * HH * WW] = acc[c];
}

extern "C" void kernel_launch(void* const* d_in, const int* in_sizes, int n_in,
                              void* d_out, int out_size, void* d_ws, size_t ws_size,
                              hipStream_t stream) {
  const float* vox       = (const float*)d_in[0];
  const float* density   = (const float*)d_in[1];
  const float* cam_rot   = (const float*)d_in[2];
  const float* cam_trans = (const float*)d_in[3];
  const float* cam_intr  = (const float*)d_in[4];
  const float* pc_xyz    = (const float*)d_in[5];
  const float* scales    = (const float*)d_in[6];
  float* out = (float*)d_out;

  const int N    = in_sizes[5] / 3;       // 6144
  const int NCAM = in_sizes[4] / 4;       // B*NC = 6
  const int B    = in_sizes[1] / N;       // 1
  const int NC   = NCAM / B;              // 6

  unsigned char* ws = (unsigned char*)d_ws;
  int* countsPtr = (int*)ws;                                   // 256 B
  int* cellord   = (int*)(ws + 256);                           // 24 KB
  float4* hdrA   = (float4*)(ws + 32768);                      // 590 KB
  float4* hdrB   = (float4*)(ws + 32768 + (size_t)NCAM * HMAX * sizeof(float4));

  rank_kernel<<<dim3(NCELL/256, NCAM), 512, 0, stream>>>(
      pc_xyz, cam_rot, cam_trans, N, countsPtr, cellord);
  proj_kernel<<<dim3((HMAX + 255) / 256, NCAM), 256, 0, stream>>>(
      pc_xyz, cam_rot, cam_trans, cam_intr, density, scales, N, NC,
      countsPtr, cellord, hdrA, hdrB);
  render_kernel<<<dim3((WW/8)*(HH/4), NCAM), 64, 0, stream>>>(
      vox, hdrA, hdrB, countsPtr, out, N, NC);
}

// Round 15
// 82.410 us; speedup vs baseline: 1.0121x; 1.0121x over previous
//
#include <hip/hip_runtime.h>

#define NEARV    0.2f
#define LOWPASSV 0.3f

constexpr int HH = 80, WW = 80;
constexpr int CFE = 32;          // feature channels
constexpr int NZ = 6;            // z-levels per (x,y) cell (grid 32x32x6)

constexpr int NCELL = 1024;      // N / NZ
constexpr int HMAX = NCELL * NZ; // 6144 header slots per camera

typedef unsigned long long u64;
typedef unsigned int u32;

// ------- Kernel R: rank-by-counting cell argsort (R11/R13 verbatim, ~8.5us) -------
// Keys (HW-verified R7-R14, absmax bit-identical): depth in (0.2,32) ->
// floatbits - 0x3E000000 monotone 26-bit; >>4 to 22 bits; packed =
// (key22<<10)|cell UNIQUE -> rank(e) = #{keys < key(e)} == stable depth
// argsort position; ranks are a permutation -> cellord[rank] = cell.
__global__ __launch_bounds__(512) void rank_kernel(
    const float* __restrict__ pc_xyz, const float* __restrict__ cam_rot,
    const float* __restrict__ cam_trans, int N,
    int* __restrict__ counts, int* __restrict__ cellord)
{
  __shared__ u32 sk[NCELL];              // 4 KB
  __shared__ u32 wred[8];

  const int cam = blockIdx.y;
  const int tid = threadIdx.x;           // 0..511
  const float* R = cam_rot + cam*9;
  const float R20 = R[6], R21 = R[7], R22 = R[8];
  const float t2  = cam_trans[cam*3+2];

  int vcnt = 0;
  #pragma unroll
  for (int e2 = 0; e2 < NCELL/512; ++e2) {
    const int cell = e2*512 + tid;
    const int i0 = cell * NZ;
    u32 key22 = 0x3FFFFFu;               // invalid marker: sorts last
    if (i0 < N) {
      float c2 = R20*pc_xyz[i0*3+0] + R21*pc_xyz[i0*3+1] + R22*pc_xyz[i0*3+2] + t2;
      if (c2 > NEARV) {
        u32 b = __float_as_uint(c2) - 0x3E000000u;   // monotone, 26 bits
        b = b < 0x03FFFF00u ? b : 0x03FFFF00u;       // clamp below marker
        key22 = b >> 4;                              // 22 bits, < 0x3FFFFF
        ++vcnt;
      }
    }
    sk[cell] = (key22 << 10) | (u32)cell;
  }
  __syncthreads();

  // rank: threads (2c, 2c+1) handle cell c; each counts half the keys
  const int cell = blockIdx.x * 256 + (tid >> 1);
  const u32 mykey = sk[cell];
  const uint4* k4 = (const uint4*)sk;
  const int h0 = (tid & 1) * (NCELL/8);  // half offset in uint4 units
  int rank = 0;
  #pragma unroll 8
  for (int i = 0; i < NCELL/8; ++i) {
    const uint4 kv = k4[h0 + i];
    rank += (int)(kv.x < mykey) + (int)(kv.y < mykey)
          + (int)(kv.z < mykey) + (int)(kv.w < mykey);
  }
  rank += __shfl_xor(rank, 1, 64);       // combine halves (same wave)

  if ((tid & 1) == 0)
    cellord[(size_t)cam * NCELL + rank] = cell;

  if (blockIdx.x == 0) {
    #pragma unroll
    for (int off = 32; off > 0; off >>= 1) vcnt += __shfl_down(vcnt, off, 64);
    if ((tid & 63) == 0) wred[tid >> 6] = (u32)vcnt;
    __syncthreads();
    if (tid == 0) {
      u32 tot = 0;
      #pragma unroll
      for (int w = 0; w < 8; ++w) tot += wred[w];
      counts[cam] = (int)tot * NZ;
    }
  }
}

// ------------- Kernel P: wide projection with BAKED alpha constants (R14 verbatim) -------------
// One thread per (camera, sorted gaussian), 144 blocks spread across CUs.
// Headers: hdrA=(u, v, A2, B2), hdrB=(C2, op, r2, gi_bits) where
// A2=-0.5*ia*L, C2=-0.5*ic*L, B2=+bb*idet*L, L=log2(e). Native-exp2 alpha
// verified bit-identical on HW in R14. Off-screen gaussians get r2 = -1.
// KEY ALGEBRA (verified): scales is SCALAR per gaussian, Mcov = s*Rg,
// Rg rotation => cov = s^2 * J*J^T.
__global__ __launch_bounds__(256) void proj_kernel(
    const float* __restrict__ pc_xyz, const float* __restrict__ cam_rot,
    const float* __restrict__ cam_trans, const float* __restrict__ cam_intr,
    const float* __restrict__ density, const float* __restrict__ scales,
    int N, int NC,
    const int* __restrict__ counts, const int* __restrict__ cellord,
    float4* __restrict__ hdrA, float4* __restrict__ hdrB)
{
  const int cam = blockIdx.y;
  const int kq = blockIdx.x * 256 + threadIdx.x;
  if (kq >= counts[cam]) return;

  const int cellp = kq / NZ;
  const int n = cellord[(size_t)cam * NCELL + cellp] * NZ + (kq - cellp * NZ);

  const float* R = cam_rot + cam*9;
  const float* t = cam_trans + cam*3;
  const float* intr = cam_intr + cam*4;
  const float fx = intr[0], fy = intr[1], cx = intr[2], cy = intr[3];
  const int b = cam / NC;

  const float p0 = pc_xyz[n*3+0], p1 = pc_xyz[n*3+1], p2 = pc_xyz[n*3+2];
  const float c0 = R[0]*p0 + R[1]*p1 + R[2]*p2 + t[0];
  const float c1 = R[3]*p0 + R[4]*p1 + R[5]*p2 + t[1];
  const float c2 = R[6]*p0 + R[7]*p1 + R[8]*p2 + t[2];
  const float tz = fmaxf(c2, 1e-6f);
  const float itz = 1.0f / tz;
  const float u = fx*c0*itz + cx;
  const float v = fy*c1*itz + cy;
  const float j00 = fx*itz, j02 = -(fx*c0*itz)*itz;
  const float j11 = fy*itz, j12 = -(fy*c1*itz)*itz;
  const float s = expf(scales[n]);
  const float s2 = s*s;
  const float cov00 = s2*(j00*j00 + j02*j02);
  const float cov01 = s2*(j02*j12);
  const float cov11 = s2*(j11*j11 + j12*j12);
  const float a = cov00 + LOWPASSV, bb = cov01, cc = cov11 + LOWPASSV;
  const float det = a*cc - bb*bb;
  const float idet = 1.0f / det;
  // conservative cull radius: dist^2 > r2 <=> power < -16 everywhere
  const float mid = 0.5f*(a + cc);
  const float dd = sqrtf(fmaxf(mid*mid - det, 0.f));
  float r2 = 32.f * (mid + dd);
  const float dens = density[(size_t)b*N + n];
  const float op = fmaxf(dens, 0.f) + log1pf(expf(-fabsf(dens)));  // softplus
  // whole-SCREEN rect cull -> r2 = -1 disables this gaussian in the render
  const float sx = fminf(fmaxf(u, 0.f), (float)(WW-1)) - u;
  const float sy = fminf(fmaxf(v, 0.f), (float)(HH-1)) - v;
  if (sx*sx + sy*sy > r2) r2 = -1.0f;

  const float L = 1.4426950408889634f;   // log2(e)
  const float A2 = -0.5f * (cc*idet) * L;
  const float C2 = -0.5f * (a*idet)  * L;
  const float B2 =         (bb*idet) * L;

  hdrA[(size_t)cam * HMAX + kq] = make_float4(u, v, A2, B2);
  hdrB[(size_t)cam * HMAX + kq] = make_float4(C2, op, r2, __int_as_float(n));
}

// ---------- Kernel B: readlane-alpha compositing, 16x4 single-wave tiles (R15) ----------
// R14 post-mortem: render ~29us invariant under VALU/barrier/prefetch edits.
// Per-CU pipe model: T_LDS = 4.7 waves/CU x 515 surv x 6.3 b128 x ~5cy ~ 32us
// (matches); T_VALU ~ 17us. RENDER IS CU-LEVEL LDS-PIPE BOUND. R5's
// channel-split was neutral because it halved reads/wave but doubled
// waves/CU. R15 cuts per-CU LDS ~45%:
//  (1) cA/cB ELIMINATED: survivor headers live in lane registers (a0_/b0_);
//      per group extract 8 source lanes from the uniform ballot mask
//      (ctzll chain, SALU) and v_readlane the 6 alpha scalars -- VALU pipe,
//      not DS. Bit-identical inputs -> bit-identical alpha. Only cgi (4B)
//      still transits LDS.
//  (2) tile back to 16x4 / 64px / single wave (R2 geometry): waves/CU
//      4.7 -> 2.35, halving per-CU sfeat reads AND alpha duplication.
// Single-wave block, no __syncthreads (R13/R14, HW-verified bit-identical).
__global__ __launch_bounds__(64) void render_kernel(
    const float* __restrict__ vox,
    const float4* __restrict__ hdrA, const float4* __restrict__ hdrB,
    const int* __restrict__ counts,
    float* __restrict__ out, int N, int NC)
{
  __shared__ int   cgi[64];             // compacted survivor original index
  __shared__ float4 sfeat[64];          // current 8 survivors' features (1 KB)

  const int cam = blockIdx.y;
  const int tile = blockIdx.x;          // 5 x 20 tiles of 16x4 px
  const int tx = tile % (WW/16), ty = tile / (WW/16);
  const int lane = threadIdx.x;
  const int lx = lane & 15, ly = lane >> 4;
  const int px = tx*16 + lx, py = ty*4 + ly;
  const float fpx = (float)px, fpy = (float)py;
  const float tx0 = (float)(tx*16), tx1 = tx0 + 15.f;
  const float ty0 = (float)(ty*4),  ty1 = ty0 + 3.f;
  const int count = counts[cam];
  const int b = cam / NC;
  const float4* hA = hdrA + (size_t)cam * HMAX;
  const float4* hB = hdrB + (size_t)cam * HMAX;
  const float4* voxb = (const float4*)vox + (size_t)b * N * (CFE/4);

  float acc[CFE];                       // full 32 channels per pixel-lane
  #pragma unroll
  for (int i = 0; i < CFE; ++i) acc[i] = 0.f;
  float T = 1.0f;
  bool done = false;

#define RDLN(x, l) __uint_as_float(__builtin_amdgcn_readlane(__float_as_uint(x), (l)))

#define LOAD4(Aarr, Barr, base_) do {                                   \
    _Pragma("unroll")                                                   \
    for (int d_ = 0; d_ < 4; ++d_) {                                    \
      const int kn_ = min((base_) + d_*64 + lane, count - 1);           \
      Aarr[d_] = hA[kn_]; Barr[d_] = hB[kn_];                           \
    } } while (0)

// one 64-gaussian chunk: cull -> cgi compact -> readlane-alpha composite.
// NO __syncthreads: single-wave block, in-order DS unit + compiler lgkmcnt
// dependency waits give cross-lane LDS ordering (R13/R14, HW-verified).
#define PROCESS_CHUNK(k0_, a0_, b0_) do {                               \
    const int ki = (k0_) + lane;                                        \
    const float ddx = fminf(fmaxf((a0_).x, tx0), tx1) - (a0_).x;        \
    const float ddy = fminf(fmaxf((a0_).y, ty0), ty1) - (a0_).y;        \
    const bool hit = (ki < count) && (ddx*ddx + ddy*ddy <= (b0_).z);    \
    const u64 m = __ballot(hit);                                        \
    const int P = __popcll(m);                                          \
    if (P == 0) continue;                                               \
    if (hit) {                                                          \
      const int pos = (int)__popcll(m & ((1ull << lane) - 1ull));       \
      cgi[pos] = __float_as_int((b0_).w);                               \
    }                                                                   \
    __builtin_amdgcn_wave_barrier();  /* keep DS order: compact < reads */ \
    const int sl = lane >> 3, sc = lane & 7;                            \
    float4 pf = voxb[(size_t)cgi[min(sl, P - 1)] * (CFE/4) + sc];       \
    u64 mm_ = m;                      /* uniform survivor-lane stream */ \
    for (int j = 0; j < P; j += 8) {                                    \
      /* alpha from REGISTERS via readlane: no LDS on this path */      \
      float al[8];                                                      \
      _Pragma("unroll")                                                 \
      for (int qq = 0; qq < 8; ++qq) {                                  \
        const int idx = j + qq;                                         \
        int lq = 0;                                                     \
        if (mm_) { lq = (int)__builtin_ctzll(mm_); mm_ &= mm_ - 1; }    \
        const float su  = RDLN((a0_).x, lq);                            \
        const float sv  = RDLN((a0_).y, lq);                            \
        const float sA2 = RDLN((a0_).z, lq);                            \
        const float sB2 = RDLN((a0_).w, lq);                            \
        const float sC2 = RDLN((b0_).x, lq);                            \
        const float sop = RDLN((b0_).y, lq);                            \
        const float dx = fpx - su, dy = fpy - sv;                       \
        const float pl2 = sA2*(dx*dx) + sC2*(dy*dy) + sB2*(dx*dy);      \
        float av = fminf(sop * __builtin_exp2f(fminf(pl2, 0.f)), 0.99f); \
        av = (pl2 > -23.0831f) ? av : 0.f;  /* 2^-23.08 = 1.1e-7 */     \
        al[qq] = (idx < P) ? av : 0.f;                                  \
      }                                                                 \
      sfeat[lane] = pf;                 /* publish group j */           \
      if (j + 8 < P) {                  /* gather next group */          \
        const int si = min(j + 8 + sl, P - 1);                          \
        pf = voxb[(size_t)cgi[si] * (CFE/4) + sc];                      \
      }                                                                 \
      __builtin_amdgcn_wave_barrier(); /* publish < composite reads */  \
      _Pragma("unroll")                                                 \
      for (int qq = 0; qq < 8; ++qq) {                                  \
        const float w = T * al[qq];                                     \
        T -= w;                                                         \
        if (__any(w > 1e-8f)) {                                         \
          const float4* fj = &sfeat[qq * 8];                            \
          _Pragma("unroll")                                             \
          for (int c8 = 0; c8 < CFE/4; ++c8) {                          \
            const float4 fv = fj[c8];                                   \
            acc[c8*4+0] = fmaf(w, fv.x, acc[c8*4+0]);                   \
            acc[c8*4+1] = fmaf(w, fv.y, acc[c8*4+1]);                   \
            acc[c8*4+2] = fmaf(w, fv.z, acc[c8*4+2]);                   \
            acc[c8*4+3] = fmaf(w, fv.w, acc[c8*4+3]);                   \
          }                                                             \
        }                                                               \
      }                                                                 \
      if (__all(T < 1e-3f)) { done = true; break; }                     \
      __builtin_amdgcn_wave_barrier(); /* reads < next publish (WAR) */ \
    }                                                                   \
  } while (0)

  if (count > 0) {
    float4 A0x[4], B0x[4], A1x[4], B1x[4];
    const int nquad = (count + 255) >> 8;   // groups of 4 chunks
    LOAD4(A0x, B0x, 0);

    for (int q = 0; q < nquad && !done; q += 2) {
      // even quad: consume A0x/B0x, prefetch next quad into A1x/B1x
      if (q + 1 < nquad) LOAD4(A1x, B1x, (q+1)*256);
      #pragma unroll
      for (int d = 0; d < 4; ++d) {
        if (done) break;
        const int k0 = q*256 + d*64;
        if (k0 >= count) break;
        PROCESS_CHUNK(k0, A0x[d], B0x[d]);
      }
      if (done || q + 1 >= nquad) break;
      // odd quad: consume A1x/B1x, prefetch next quad into A0x/B0x
      if (q + 2 < nquad) LOAD4(A0x, B0x, (q+2)*256);
      #pragma unroll
      for (int d = 0; d < 4; ++d) {
        if (done) break;
        const int k0 = (q+1)*256 + d*64;
        if (k0 >= count) break;
        PROCESS_CHUNK(k0, A1x[d], B1x[d]);
      }
    }
  }
#undef PROCESS_CHUNK
#undef LOAD4
#undef RDLN

  // write this lane's pixel: all 32 channels
  float* ob = out + (((size_t)cam * CFE) * HH + py) * WW + px;
  #pragma unroll
  for (int c = 0; c < CFE; ++c) ob[(size_t)c * HH * WW] = acc[c];
}

extern "C" void kernel_launch(void* const* d_in, const int* in_sizes, int n_in,
                              void* d_out, int out_size, void* d_ws, size_t ws_size,
                              hipStream_t stream) {
  const float* vox       = (const float*)d_in[0];
  const float* density   = (const float*)d_in[1];
  const float* cam_rot   = (const float*)d_in[2];
  const float* cam_trans = (const float*)d_in[3];
  const float* cam_intr  = (const float*)d_in[4];
  const float* pc_xyz    = (const float*)d_in[5];
  const float* scales    = (const float*)d_in[6];
  float* out = (float*)d_out;

  const int N    = in_sizes[5] / 3;       // 6144
  const int NCAM = in_sizes[4] / 4;       // B*NC = 6
  const int B    = in_sizes[1] / N;       // 1
  const int NC   = NCAM / B;              // 6

  unsigned char* ws = (unsigned char*)d_ws;
  int* countsPtr = (int*)ws;                                   // 256 B
  int* cellord   = (int*)(ws + 256);                           // 24 KB
  float4* hdrA   = (float4*)(ws + 32768);                      // 590 KB
  float4* hdrB   = (float4*)(ws + 32768 + (size_t)NCAM * HMAX * sizeof(float4));

  rank_kernel<<<dim3(NCELL/256, NCAM), 512, 0, stream>>>(
      pc_xyz, cam_rot, cam_trans, N, countsPtr, cellord);
  proj_kernel<<<dim3((HMAX + 255) / 256, NCAM), 256, 0, stream>>>(
      pc_xyz, cam_rot, cam_trans, cam_intr, density, scales, N, NC,
      countsPtr, cellord, hdrA, hdrB);
  render_kernel<<<dim3((WW/16)*(HH/4), NCAM), 64, 0, stream>>>(
      vox, hdrA, hdrB, countsPtr, out, N, NC);
}